// Round 8
// baseline (341.159 us; speedup 1.0000x reference)
//
#include <hip/hip_runtime.h>

#define NEG_SLOPE 0.2f
#define NPB 256          // nodes per dst-bucket (bucket = dst >> 8)
#define CHUNK 4096       // edges per partition block

typedef _Float16 f16x8 __attribute__((ext_vector_type(8)));
typedef _Float16 f16x4 __attribute__((ext_vector_type(4)));
typedef _Float16 f16x2 __attribute__((ext_vector_type(2)));
typedef float    f32x4 __attribute__((ext_vector_type(4)));

#if defined(__has_builtin)
#if __has_builtin(__builtin_amdgcn_fdot2)
#define HAVE_FDOT2 1
#endif
#if __has_builtin(__builtin_amdgcn_exp2f)
#define EXP2F(v) __builtin_amdgcn_exp2f(v)
#else
#define EXP2F(v) exp2f(v)
#endif
#endif
#ifndef EXP2F
#define EXP2F(v) exp2f(v)
#endif

// ---------------------------------------------------------------------------
// prep: W transpose->fp16 (blocks 0..255), x fp32->fp16 hi/lo split,
// bucket histogram (last blocks). bcnt zeroed by hipMemsetAsync beforehand.
// ---------------------------------------------------------------------------
__global__ __launch_bounds__(256) void prep_kernel(
    const float* __restrict__ W0, const float* __restrict__ W1,
    const float* __restrict__ W2, const float* __restrict__ W3,
    _Float16* __restrict__ wt,
    const float* __restrict__ x, _Float16* __restrict__ xh,
    _Float16* __restrict__ xlo, int total, int nxblocks,
    const int* __restrict__ ei, int* __restrict__ bcnt, int E)
{
    __shared__ int bh[256];
    int t = threadIdx.x;
    int bx = blockIdx.x;
    if (bx < 256) {
        int idx = bx * 256 + t;     // 4*128*128
        int m = idx >> 14;
        int k = (idx >> 7) & 127;
        int n = idx & 127;
        const float* W = (m == 0) ? W0 : (m == 1) ? W1 : (m == 2) ? W2 : W3;
        wt[m * 16384 + n * 128 + k] = (_Float16)W[k * 128 + n];
    } else if (bx < 256 + nxblocks) {
        int i = (bx - 256) * 256 + t;
        if (i * 2 < total) {
            float2 f = *(const float2*)(x + (size_t)i * 2);
            _Float16 h0 = (_Float16)f.x, h1 = (_Float16)f.y;
            _Float16 l0 = (_Float16)(f.x - (float)h0), l1 = (_Float16)(f.y - (float)h1);
            *(f16x2*)(xh  + (size_t)i * 2) = (f16x2){h0, h1};
            *(f16x2*)(xlo + (size_t)i * 2) = (f16x2){l0, l1};
        }
    } else {
        bh[t] = 0;
        __syncthreads();
        int base = (bx - 256 - nxblocks) * CHUNK;
#pragma unroll
        for (int j = 0; j < CHUNK / 256; j++) {
            int e = base + t + j * 256;
            if (e < E) atomicAdd(&bh[ei[E + e] >> 8], 1);
        }
        __syncthreads();
        if (bh[t]) atomicAdd(&bcnt[t], bh[t]);
    }
}

// ---------------------------------------------------------------------------
// fp16 MFMA GEMM, LDS-staged W (34 KB). C = Ah@W + Al@W, fp32 acc.
// Both outputs fp16 (y==0 -> Cl, y==1 -> Cr).
// ---------------------------------------------------------------------------
__global__ __launch_bounds__(256) void gemm_f16_kernel(
    const _Float16* __restrict__ Ahi, const _Float16* __restrict__ Alo,
    const _Float16* __restrict__ Wt0, const _Float16* __restrict__ Wt1,
    _Float16* __restrict__ Cl, _Float16* __restrict__ Cr, int N)
{
    const _Float16* Wt = blockIdx.y ? Wt1 : Wt0;
    _Float16* C = blockIdx.y ? Cr : Cl;

    __shared__ _Float16 ldsW[128 * 136];   // row stride 272 B

    const int tid = threadIdx.x;
    const int wave = tid >> 6;
    const int lane = tid & 63;
    const int mrow = lane & 15;
    const int quad = lane >> 4;
    const int rbase = blockIdx.x * 128 + wave * 32;

    const int sn = tid >> 1, shf = tid & 1;
    float4 stg[8];
    {
        const float4* g = (const float4*)(Wt + sn * 128 + shf * 64);
#pragma unroll
        for (int j = 0; j < 8; j++) stg[j] = g[j];
    }

    f16x8 ah[2][4], al[2][4];
#pragma unroll
    for (int rt = 0; rt < 2; rt++) {
        int r = rbase + rt * 16 + mrow;
        if (r > N - 1) r = N - 1;
        const _Float16* pa = Ahi + (size_t)r * 128 + quad * 8;
        const _Float16* pl = Alo + (size_t)r * 128 + quad * 8;
#pragma unroll
        for (int s = 0; s < 4; s++) {
            ah[rt][s] = *(const f16x8*)(pa + s * 32);
            al[rt][s] = *(const f16x8*)(pl + s * 32);
        }
    }

    {
        float4* d = (float4*)&ldsW[sn * 136 + shf * 64];
#pragma unroll
        for (int j = 0; j < 8; j++) d[j] = stg[j];
    }

    f32x4 acc[2][8];
#pragma unroll
    for (int rt = 0; rt < 2; rt++)
#pragma unroll
        for (int c = 0; c < 8; c++) acc[rt][c] = (f32x4){0.f, 0.f, 0.f, 0.f};

    __syncthreads();

#pragma unroll
    for (int s = 0; s < 4; s++) {
#pragma unroll
        for (int c = 0; c < 8; c++) {
            f16x8 bw = *(const f16x8*)&ldsW[(c * 16 + mrow) * 136 + s * 32 + quad * 8];
            acc[0][c] = __builtin_amdgcn_mfma_f32_16x16x32_f16(ah[0][s], bw, acc[0][c], 0, 0, 0);
            acc[0][c] = __builtin_amdgcn_mfma_f32_16x16x32_f16(al[0][s], bw, acc[0][c], 0, 0, 0);
            acc[1][c] = __builtin_amdgcn_mfma_f32_16x16x32_f16(ah[1][s], bw, acc[1][c], 0, 0, 0);
            acc[1][c] = __builtin_amdgcn_mfma_f32_16x16x32_f16(al[1][s], bw, acc[1][c], 0, 0, 0);
        }
    }

    // D mapping: col = lane&15, row = quad*4 + reg
#pragma unroll
    for (int rt = 0; rt < 2; rt++)
#pragma unroll
        for (int i = 0; i < 4; i++) {
            int r = rbase + rt * 16 + quad * 4 + i;
            if (r < N) {
                _Float16* cr = C + (size_t)r * 128 + mrow;
#pragma unroll
                for (int c = 0; c < 8; c++) cr[c * 16] = (_Float16)acc[rt][c][i];
            }
        }
}

// ---------------------------------------------------------------------------
// Bucketed CSR build: scan, partition, per-bucket counting sort.
// ---------------------------------------------------------------------------
__global__ __launch_bounds__(256) void scanB_kernel(
    const int* __restrict__ bcnt, int* __restrict__ bstart,
    int* __restrict__ gcursor, int NB, int E)
{
    __shared__ int s[256];
    int t = threadIdx.x;
    int v = (t < NB) ? bcnt[t] : 0;
    s[t] = v;
    __syncthreads();
    for (int off = 1; off < 256; off <<= 1) {
        int u = (t >= off) ? s[t - off] : 0;
        __syncthreads();
        s[t] += u;
        __syncthreads();
    }
    if (t < NB) { bstart[t] = s[t] - v; gcursor[t] = s[t] - v; }
    if (t == 0) bstart[NB] = E;
}

__global__ __launch_bounds__(256) void passA_kernel(
    const int* __restrict__ ei, int* __restrict__ gcursor,
    int2* __restrict__ staging, int E)
{
    __shared__ int bh[256];
    __shared__ int bbase[256];
    int t = threadIdx.x;
    bh[t] = 0;
    __syncthreads();
    int base = blockIdx.x * CHUNK;
    int srcv[16], dstv[16], rb[16];
#pragma unroll
    for (int j = 0; j < 16; j++) {
        int e = base + t + j * 256;
        if (e < E) {
            int d = ei[E + e];
            srcv[j] = ei[e];
            dstv[j] = d;
            int bk = d >> 8;
            int r = atomicAdd(&bh[bk], 1);
            rb[j] = (r << 8) | bk;
        } else rb[j] = -1;
    }
    __syncthreads();
    if (bh[t]) bbase[t] = atomicAdd(&gcursor[t], bh[t]);
    __syncthreads();
#pragma unroll
    for (int j = 0; j < 16; j++) {
        if (rb[j] >= 0) {
            int bk = rb[j] & 255, r = rb[j] >> 8;
            staging[bbase[bk] + r] = make_int2(srcv[j], dstv[j]);
        }
    }
}

__global__ __launch_bounds__(256) void passB_kernel(
    const int2* __restrict__ staging, const int* __restrict__ bstart,
    int* __restrict__ start, int* __restrict__ sorted_src, int N, int E)
{
    __shared__ int lhist[256], lscan[256], lcur[256];
    int b = blockIdx.x, t = threadIdx.x;
    int r0 = bstart[b], r1 = bstart[b + 1];
    lhist[t] = 0;
    __syncthreads();
    for (int i = r0 + t; i < r1; i += 256) atomicAdd(&lhist[staging[i].y & 255], 1);
    __syncthreads();
    int v = lhist[t];
    lscan[t] = v;
    __syncthreads();
    for (int off = 1; off < 256; off <<= 1) {
        int u = (t >= off) ? lscan[t - off] : 0;
        __syncthreads();
        lscan[t] += u;
        __syncthreads();
    }
    int excl = lscan[t] - v;
    int node = b * NPB + t;
    if (node < N) start[node] = r0 + excl;
    lcur[t] = excl;
    if (b == 0 && t == 0) start[N] = E;
    __syncthreads();
    for (int i = r0 + t; i < r1; i += 256) {
        int2 p = staging[i];
        int rank = atomicAdd(&lcur[p.y & 255], 1);
        sorted_src[r0 + rank] = p.x;
    }
}

// ---------------------------------------------------------------------------
// Fused score+softmax+aggregate v3: one wave per dst node; each QUARTER-wave
// (16 lanes x f16x8) owns an edge -> 4 edges/wave-iter, dwordx4 gathers,
// 4-level (H=1) / 3-level (H=2) swizzle reduce, one v_exp per 4 edges.
// Self-loop = virtual edge 0 (handled in masked k=0 prologue).
// att pre-scaled by log2(e) -> exp2. Head = bit3 of (lane&15); no reduce
// mask touches bit 3, so heads stay separated.
// ---------------------------------------------------------------------------
template <int H, bool BFOUT>
__global__ __launch_bounds__(256) void gat_fused_kernel(
    const _Float16* __restrict__ xl, const _Float16* __restrict__ xr,
    const float* __restrict__ att, const float* __restrict__ bias,
    const int* __restrict__ start, const int* __restrict__ sorted_src,
    float* __restrict__ outf, _Float16* __restrict__ oh,
    _Float16* __restrict__ ol, int N)
{
    int node = blockIdx.x * 4 + (threadIdx.x >> 6);
    if (node >= N) return;
    const int lane = threadIdx.x & 63;
    const int g    = lane >> 4;        // edge-slot group 0..3
    const int cl   = lane & 15;        // col chunk: cols cl*8 .. cl*8+7
    const int RED  = (H == 2) ? 4 : 8; // xor masks 1..RED within 16-lane group
    const _Float16 NS = (_Float16)NEG_SLOPE;
    const float L2E = 1.44269504f;

    const f16x8 b8 = *(const f16x8*)(xr + (size_t)node * 128 + cl * 8);
    f16x8 av;
#pragma unroll
    for (int i = 0; i < 8; i++) av[i] = (_Float16)(att[cl * 8 + i] * L2E);
#if defined(HAVE_FDOT2)
    f16x2 av0 = __builtin_shufflevector(av, av, 0, 1);
    f16x2 av1 = __builtin_shufflevector(av, av, 2, 3);
    f16x2 av2 = __builtin_shufflevector(av, av, 4, 5);
    f16x2 av3 = __builtin_shufflevector(av, av, 6, 7);
#endif

    auto score = [&](f16x8 a) -> float {
        f16x8 t = a + b8;
        f16x8 u = __builtin_elementwise_max(t, t * NS);
#if defined(HAVE_FDOT2)
        float p = __builtin_amdgcn_fdot2(__builtin_shufflevector(u, u, 0, 1), av0, 0.0f, false);
        p = __builtin_amdgcn_fdot2(__builtin_shufflevector(u, u, 2, 3), av1, p, false);
        p = __builtin_amdgcn_fdot2(__builtin_shufflevector(u, u, 4, 5), av2, p, false);
        p = __builtin_amdgcn_fdot2(__builtin_shufflevector(u, u, 6, 7), av3, p, false);
        return p;
#else
        float p = 0.f;
#pragma unroll
        for (int i = 0; i < 8; i++) p += (float)u[i] * (float)av[i];
        return p;
#endif
    };

    float acc[8];
#pragma unroll
    for (int i = 0; i < 8; i++) acc[i] = 0.f;
    float den = 0.f;

    const int s0 = start[node];
    const int s1 = start[node + 1];
    const int M  = s1 - s0 + 1;        // incl. self-loop at iv==0
    const int Ksafe = M >> 2;          // k < Ksafe: all 4 groups valid
    const int K     = (M + 3) >> 2;

    // k = 0: masked + self-loop select (only iteration that needs either
    // when M >= 4; for M < 4 it is also the only iteration besides none)
    {
        int iv = g;
        bool valid = iv < M;
        int ld = sorted_src[s0 + (g > 0 ? g - 1 : 0)];   // padded array
        int src = (g == 0) ? node : (valid ? ld : node);
        f16x8 a = *(const f16x8*)(xl + (size_t)src * 128 + cl * 8);
        float p = score(a);
#pragma unroll
        for (int m = 1; m <= RED; m <<= 1) p += __shfl_xor(p, m, 64);
        float e = valid ? EXP2F(p) : 0.f;
        den += e;
#pragma unroll
        for (int i = 0; i < 8; i++) acc[i] += (float)a[i] * e;
    }

    int k = 1;
    for (; k + 4 <= Ksafe; k += 4) {
        int src[4]; f16x8 a[4]; float p[4];
#pragma unroll
        for (int j = 0; j < 4; j++)
            src[j] = sorted_src[s0 + 4 * (k + j) + g - 1];
#pragma unroll
        for (int j = 0; j < 4; j++)
            a[j] = *(const f16x8*)(xl + (size_t)src[j] * 128 + cl * 8);
#pragma unroll
        for (int j = 0; j < 4; j++) p[j] = score(a[j]);
#pragma unroll
        for (int m = 1; m <= RED; m <<= 1) {
#pragma unroll
            for (int j = 0; j < 4; j++) p[j] += __shfl_xor(p[j], m, 64);
        }
#pragma unroll
        for (int j = 0; j < 4; j++) {
            float e = EXP2F(p[j]);
            den += e;
#pragma unroll
            for (int i = 0; i < 8; i++) acc[i] += (float)a[j][i] * e;
        }
    }
    for (; k < Ksafe; k++) {
        int src = sorted_src[s0 + 4 * k + g - 1];
        f16x8 a = *(const f16x8*)(xl + (size_t)src * 128 + cl * 8);
        float p = score(a);
#pragma unroll
        for (int m = 1; m <= RED; m <<= 1) p += __shfl_xor(p, m, 64);
        float e = EXP2F(p);
        den += e;
#pragma unroll
        for (int i = 0; i < 8; i++) acc[i] += (float)a[i] * e;
    }
    for (; k < K; k++) {               // masked tail (at most one iteration)
        int iv = 4 * k + g;
        bool valid = iv < M;
        int ld = sorted_src[s0 + iv - 1];   // iv >= 4 here; padded array
        int src = valid ? ld : node;
        f16x8 a = *(const f16x8*)(xl + (size_t)src * 128 + cl * 8);
        float p = score(a);
#pragma unroll
        for (int m = 1; m <= RED; m <<= 1) p += __shfl_xor(p, m, 64);
        float e = valid ? EXP2F(p) : 0.f;
        den += e;
#pragma unroll
        for (int i = 0; i < 8; i++) acc[i] += (float)a[i] * e;
    }

    // merge the 4 groups (xor 16 and 32 never touch head bit 3)
    den += __shfl_xor(den, 16, 64);
    den += __shfl_xor(den, 32, 64);
#pragma unroll
    for (int i = 0; i < 8; i++) {
        acc[i] += __shfl_xor(acc[i], 16, 64);
        acc[i] += __shfl_xor(acc[i], 32, 64);
    }

    float inv = 1.0f / den;
    if (lane < 16) {
        float o[8];
        float4 bi0 = *(const float4*)(bias + cl * 8);
        float4 bi1 = *(const float4*)(bias + cl * 8 + 4);
        o[0] = acc[0] * inv + bi0.x; o[1] = acc[1] * inv + bi0.y;
        o[2] = acc[2] * inv + bi0.z; o[3] = acc[3] * inv + bi0.w;
        o[4] = acc[4] * inv + bi1.x; o[5] = acc[5] * inv + bi1.y;
        o[6] = acc[6] * inv + bi1.z; o[7] = acc[7] * inv + bi1.w;
        if (BFOUT) {   // next layer's A: fp16 hi+lo split
            f16x8 hv, lv;
#pragma unroll
            for (int i = 0; i < 8; i++) {
                _Float16 h = (_Float16)o[i];
                hv[i] = h;
                lv[i] = (_Float16)(o[i] - (float)h);
            }
            *(f16x8*)(oh + (size_t)node * 128 + cl * 8) = hv;
            *(f16x8*)(ol + (size_t)node * 128 + cl * 8) = lv;
        } else {
            *(float4*)(outf + (size_t)node * 128 + cl * 8)     = make_float4(o[0], o[1], o[2], o[3]);
            *(float4*)(outf + (size_t)node * 128 + cl * 8 + 4) = make_float4(o[4], o[5], o[6], o[7]);
        }
    }
}

// ---------------------------------------------------------------------------
extern "C" void kernel_launch(void* const* d_in, const int* in_sizes, int n_in,
                              void* d_out, int out_size, void* d_ws, size_t ws_size,
                              hipStream_t stream)
{
    const float* x    = (const float*)d_in[0];
    const int*   ei   = (const int*)d_in[1];
    const float* Wl1  = (const float*)d_in[3];
    const float* Wr1  = (const float*)d_in[4];
    const float* att1 = (const float*)d_in[5];
    const float* b1   = (const float*)d_in[6];
    const float* Wl2  = (const float*)d_in[7];
    const float* Wr2  = (const float*)d_in[8];
    const float* att2 = (const float*)d_in[9];
    const float* b2   = (const float*)d_in[10];
    float* out = (float*)d_out;

    const int N  = in_sizes[0] / 128;
    const int E  = in_sizes[1] / 2;
    const int NB = (N + NPB - 1) / NPB;

    const size_t nf = (size_t)N * 128;
    _Float16* xlf  = (_Float16*)d_ws;                 // nf fp16 (gather array)
    _Float16* xrf  = xlf + nf;                        // nf fp16
    _Float16* ah   = xrf + nf;                        // nf fp16 (A hi: x, then h)
    _Float16* al   = ah + nf;                         // nf fp16 (A lo)
    _Float16* wt   = al + nf;                         // 4*16384 fp16
    int* bcnt      = (int*)(wt + 4 * 16384);          // 256
    int* bstart    = bcnt + 256;                      // NB+1 (<=257)
    int* gcursor   = bstart + 257;                    // 256
    int* start     = gcursor + 256;                   // N+1
    size_t stgoff  = ((size_t)(start + N + 1) + 7) & ~(size_t)7;
    int2* staging  = (int2*)stgoff;                   // E int2
    int* sorted_src = (int*)(staging + E);            // E + 64 (padded)

    const int grid_chunk = (E + CHUNK - 1) / CHUNK;
    const int node_grid  = (N + 3) / 4;
    const int gemm_gx    = (N + 127) / 128;
    const int split_grid = (int)((nf / 2 + 255) / 256);

    // ---- prep (+hist) ----
    hipMemsetAsync(bcnt, 0, 256 * sizeof(int), stream);
    prep_kernel<<<256 + split_grid + grid_chunk, 256, 0, stream>>>(
        Wl1, Wr1, Wl2, Wr2, wt, x, ah, al, (int)nf, split_grid, ei, bcnt, E);

    // ---- bucketed CSR build (shared by both layers) ----
    scanB_kernel<<<1, 256, 0, stream>>>(bcnt, bstart, gcursor, NB, E);
    passA_kernel<<<grid_chunk, 256, 0, stream>>>(ei, gcursor, staging, E);
    passB_kernel<<<NB, 256, 0, stream>>>(staging, bstart, start, sorted_src, N, E);

    // ---- Layer 1: heads=2, ch=64 ----
    gemm_f16_kernel<<<dim3(gemm_gx, 2), 256, 0, stream>>>(
        ah, al, wt + 0 * 16384, wt + 1 * 16384, xlf, xrf, N);
    gat_fused_kernel<2, true><<<node_grid, 256, 0, stream>>>(
        xlf, xrf, att1, b1, start, sorted_src, nullptr, ah, al, N);

    // ---- Layer 2: heads=1, ch=128 ----
    gemm_f16_kernel<<<dim3(gemm_gx, 2), 256, 0, stream>>>(
        ah, al, wt + 2 * 16384, wt + 3 * 16384, xlf, xrf, N);
    gat_fused_kernel<1, false><<<node_grid, 256, 0, stream>>>(
        xlf, xrf, att2, b2, start, sorted_src, out, nullptr, nullptr, N);
}